// Round 3
// baseline (360.055 us; speedup 1.0000x reference)
//
#include <hip/hip_runtime.h>
#include <hip/hip_cooperative_groups.h>
#include <math.h>

namespace cg = cooperative_groups;

// Problem constants (reference: B=4, N=2048, H=5, L=3)
#define B_ 4
#define N_ 2048
#define H_ 5
#define L_ 3
#define EPS_ 1e-6f

constexpr int RPW = 4;             // rows per wave (register-tiled)
constexpr int WAVES = 4;           // waves per block (256 threads)
constexpr int RPB = RPW * WAVES;   // rows per block = 16
constexpr int CHUNKS = N_ / RPB;   // 128 blocks per batch row
constexpr int ITERS = N_ / 64;     // 32 j-elements per lane
constexpr float LOG2E = 1.4426950408889634f;

// Whole 3-layer encoder in one cooperative kernel.
// Per layer:
//   a[b,i] = sum_h w0[h] * (Num_i - e_ii*v_i) / D_i     (attention, rank-1 scores)
//   out    = cur + gamma*(a-mean)/(sqrt(var_unbiased)+eps) + beta
// LayerNorm stats via per-block (sum,sumsq) partials in d_ws + grid sync.
__global__ __launch_bounds__(256, 2) void fused_kernel(
    const float* __restrict__ x,      // [B,N]
    const float* __restrict__ WQ,     // [L,H,N]
    const float* __restrict__ WK,     // [L,H,N]
    const float* __restrict__ WV,     // [L,H,N]
    const float* __restrict__ W0,     // [L,H]
    const float* __restrict__ gamma,  // [N]
    const float* __restrict__ beta,   // [N]
    float* __restrict__ out,          // [B,N]
    float2* __restrict__ part)        // [B, CHUNKS] (sum, sumsq) partials
{
  cg::grid_group grid = cg::this_grid();

  __shared__ float xb[N_];     // current residual row (8 KB)
  __shared__ float2 kv[N_];    // (k'_j, v_j) for current head (16 KB)
  __shared__ float2 red4[WAVES];

  const int b = blockIdx.x / CHUNKS;
  const int chunk = blockIdx.x % CHUNKS;
  const int i0 = chunk * RPB;
  const int tid = threadIdx.x;
  const int wave = tid >> 6;
  const int lane = tid & 63;

  for (int l = 0; l < L_; ++l) {
    const float* cur = (l == 0) ? (x + b * N_) : (out + b * N_);
    const float* wq = WQ + l * H_ * N_;
    const float* wk = WK + l * H_ * N_;
    const float* wv = WV + l * H_ * N_;
    const float* w0 = W0 + l * H_;

    // Stage the full residual row once per layer
    for (int j = tid; j < N_; j += 256) xb[j] = cur[j];
    __syncthreads();

    float acc[RPW];
#pragma unroll
    for (int r = 0; r < RPW; ++r) acc[r] = 0.f;

    for (int h = 0; h < H_; ++h) {
      if (h) __syncthreads();  // previous head's kv readers done
      for (int j = tid; j < N_; j += 256) {
        float oj = xb[j];
        kv[j] = make_float2(oj * wk[h * N_ + j] * LOG2E, oj * wv[h * N_ + j]);
      }
      __syncthreads();

      // Register-cache this lane's 32 (k',v) pairs
      float kx[ITERS], ky[ITERS];
#pragma unroll
      for (int it = 0; it < ITERS; ++it) {
        float2 t = kv[it * 64 + lane];
        kx[it] = t.x;
        ky[it] = t.y;
      }

      float s[RPW], d[RPW], n[RPW];
#pragma unroll
      for (int r = 0; r < RPW; ++r) {
        const int i = i0 + wave * RPW + r;
        s[r] = xb[i] * wq[h * N_ + i];
        d[r] = 0.f;
        n[r] = 0.f;
      }

#pragma unroll
      for (int it = 0; it < ITERS; ++it) {
#pragma unroll
        for (int r = 0; r < RPW; ++r) {
          float e = __builtin_amdgcn_exp2f(s[r] * kx[it]);
          d[r] += e;
          n[r] = fmaf(e, ky[it], n[r]);
        }
      }

      const float w0h = w0[h];
#pragma unroll
      for (int r = 0; r < RPW; ++r) {
        float dd = d[r], nn = n[r];
#pragma unroll
        for (int off = 32; off; off >>= 1) {
          dd += __shfl_xor(dd, off);
          nn += __shfl_xor(nn, off);
        }
        const int i = i0 + wave * RPW + r;
        float2 kvi = kv[i];
        float ed = __builtin_amdgcn_exp2f(s[r] * kvi.x);  // diagonal term
        acc[r] = fmaf(w0h, (nn - ed * kvi.y) / dd, acc[r]);
      }
    }

    // ---- LayerNorm stats: per-block (sum, sumsq) partial ----
    if (lane == 0) {
      float s1 = 0.f, s2 = 0.f;
#pragma unroll
      for (int r = 0; r < RPW; ++r) {
        s1 += acc[r];
        s2 = fmaf(acc[r], acc[r], s2);
      }
      red4[wave] = make_float2(s1, s2);
    }
    __syncthreads();
    if (tid == 0) {
      float2 t = red4[0];
      t.x += red4[1].x + red4[2].x + red4[3].x;
      t.y += red4[1].y + red4[2].y + red4[3].y;
      part[b * CHUNKS + chunk] = t;
    }
    grid.sync();

    // Every wave reduces the 128 partials for its batch row (butterfly)
    float2 p0 = part[b * CHUNKS + lane];
    float2 p1 = part[b * CHUNKS + 64 + lane];
    float s1 = p0.x + p1.x;
    float s2 = p0.y + p1.y;
#pragma unroll
    for (int off = 32; off; off >>= 1) {
      s1 += __shfl_xor(s1, off);
      s2 += __shfl_xor(s2, off);
    }
    const float mean = s1 * (1.f / N_);
    const float var = (s2 - s1 * mean) * (1.f / (N_ - 1));
    const float inv = 1.f / (sqrtf(var) + EPS_);

    if (lane == 0) {
#pragma unroll
      for (int r = 0; r < RPW; ++r) {
        const int i = i0 + wave * RPW + r;
        out[b * N_ + i] = xb[i] + gamma[i] * (acc[r] - mean) * inv + beta[i];
      }
    }
    grid.sync();  // out fully updated before next layer stages it
  }
}

extern "C" void kernel_launch(void* const* d_in, const int* in_sizes, int n_in,
                              void* d_out, int out_size, void* d_ws, size_t ws_size,
                              hipStream_t stream) {
  const float* x     = (const float*)d_in[0];
  const float* WQ    = (const float*)d_in[1];
  const float* WK    = (const float*)d_in[2];
  const float* WV    = (const float*)d_in[3];
  const float* W0    = (const float*)d_in[4];
  const float* gamma = (const float*)d_in[5];
  const float* beta  = (const float*)d_in[6];
  float* out = (float*)d_out;
  float2* part = (float2*)d_ws;

  void* args[] = {(void*)&x, (void*)&WQ, (void*)&WK, (void*)&WV, (void*)&W0,
                  (void*)&gamma, (void*)&beta, (void*)&out, (void*)&part};
  hipLaunchCooperativeKernel((const void*)fused_kernel,
                             dim3(B_ * CHUNKS), dim3(256), args, 0, stream);
}

// Round 4
// 71.635 us; speedup vs baseline: 5.0262x; 5.0262x over previous
//
#include <hip/hip_runtime.h>
#include <math.h>

// Problem constants (reference: B=4, N=2048, H=5, L=3)
#define B_ 4
#define N_ 2048
#define H_ 5
#define L_ 3
#define EPS_ 1e-6f

constexpr int RPW = 4;             // rows per wave (register-tiled)
constexpr int WAVES = 4;           // waves per block (256 threads)
constexpr int RPB = RPW * WAVES;   // rows per block = 16
constexpr int CHUNKS = N_ / RPB;   // 128 blocks per batch row
constexpr int ITERS = N_ / 64;     // 32 j-elements per lane
constexpr float LOG2E = 1.4426950408889634f;

// Attention for one layer, with the PREVIOUS layer's LayerNorm folded in:
//   cur = res_in                      (first layer)
//   cur = res_in + LN(a_prev)         (later layers; LN stats from part_prev)
//   a_out[b,i] = sum_h w0[h] * (Num_i - e_ii*v_i) / D_i   (rank-1 scores)
// Each block also writes its chunk of the updated residual (res_out) for the
// next dispatch, and its (sum,sumsq) partial of a_out for the next LN.
__global__ __launch_bounds__(256) void attn_layer_kernel(
    const float* __restrict__ res_in,     // [B,N] residual entering this layer's LN-source
    const float* __restrict__ a_prev,     // [B,N] previous attention out (null for l=0)
    const float2* __restrict__ part_prev, // [B,CHUNKS] (sum,sumsq) of a_prev
    const float* __restrict__ gamma,      // [N]
    const float* __restrict__ beta,       // [N]
    const float* __restrict__ wq,         // [H,N] layer slice
    const float* __restrict__ wk,         // [H,N]
    const float* __restrict__ wv,         // [H,N]
    const float* __restrict__ w0,         // [H]
    float* __restrict__ a_out,            // [B,N]
    float2* __restrict__ part_out,        // [B,CHUNKS]
    float* __restrict__ res_out)          // [B,N] updated residual (null for l=0)
{
  __shared__ float xb[N_];     // current residual row (8 KB)
  __shared__ float2 kv[N_];    // (k'_j, v_j) for current head (16 KB)
  __shared__ float2 red4[WAVES];

  const int bid = blockIdx.x;
  const int b = bid / CHUNKS;
  const int chunk = bid % CHUNKS;
  const int i0 = chunk * RPB;
  const int tid = threadIdx.x;
  const int wave = tid >> 6;
  const int lane = tid & 63;

  // ---- Stage cur row into LDS (folding previous LN if present) ----
  if (a_prev == nullptr) {
    for (int j = tid; j < N_; j += 256) xb[j] = res_in[b * N_ + j];
  } else {
    // Redundant per-wave reduction of the 128 partials for this batch row
    float2 p0 = part_prev[b * CHUNKS + lane];
    float2 p1 = part_prev[b * CHUNKS + 64 + lane];
    float s1 = p0.x + p1.x;
    float s2 = p0.y + p1.y;
#pragma unroll
    for (int off = 32; off; off >>= 1) {
      s1 += __shfl_xor(s1, off);
      s2 += __shfl_xor(s2, off);
    }
    const float mean = s1 * (1.f / N_);
    const float var = (s2 - s1 * mean) * (1.f / (N_ - 1));
    const float inv = 1.f / (sqrtf(var) + EPS_);
    for (int j = tid; j < N_; j += 256) {
      float r = res_in[b * N_ + j];
      float aj = a_prev[b * N_ + j];
      xb[j] = r + gamma[j] * (aj - mean) * inv + beta[j];
    }
  }
  __syncthreads();

  // Publish this block's chunk of the updated residual for the NEXT dispatch
  if (res_out != nullptr && tid < RPB)
    res_out[b * N_ + i0 + tid] = xb[i0 + tid];

  // ---- Attention (register-tiled, rank-1 scores) ----
  float acc[RPW];
#pragma unroll
  for (int r = 0; r < RPW; ++r) acc[r] = 0.f;

  for (int h = 0; h < H_; ++h) {
    if (h) __syncthreads();  // previous head's kv readers done
    for (int j = tid; j < N_; j += 256) {
      float oj = xb[j];
      kv[j] = make_float2(oj * wk[h * N_ + j] * LOG2E, oj * wv[h * N_ + j]);
    }
    __syncthreads();

    // Register-cache this lane's 32 (k',v) pairs
    float kx[ITERS], ky[ITERS];
#pragma unroll
    for (int it = 0; it < ITERS; ++it) {
      float2 t = kv[it * 64 + lane];
      kx[it] = t.x;
      ky[it] = t.y;
    }

    float s[RPW], d[RPW], n[RPW];
#pragma unroll
    for (int r = 0; r < RPW; ++r) {
      const int i = i0 + wave * RPW + r;
      s[r] = xb[i] * wq[h * N_ + i];
      d[r] = 0.f;
      n[r] = 0.f;
    }

#pragma unroll
    for (int it = 0; it < ITERS; ++it) {
#pragma unroll
      for (int r = 0; r < RPW; ++r) {
        float e = __builtin_amdgcn_exp2f(s[r] * kx[it]);
        d[r] += e;
        n[r] = fmaf(e, ky[it], n[r]);
      }
    }

    const float w0h = w0[h];
#pragma unroll
    for (int r = 0; r < RPW; ++r) {
      float dd = d[r], nn = n[r];
#pragma unroll
      for (int off = 32; off; off >>= 1) {
        dd += __shfl_xor(dd, off);
        nn += __shfl_xor(nn, off);
      }
      const int i = i0 + wave * RPW + r;
      float2 kvi = kv[i];
      float ed = __builtin_amdgcn_exp2f(s[r] * kvi.x);  // diagonal term
      acc[r] = fmaf(w0h, (nn - ed * kvi.y) / dd, acc[r]);
    }
  }

  // ---- Outputs: a_out chunk + (sum,sumsq) partial ----
  if (lane == 0) {
    float s1 = 0.f, s2 = 0.f;
#pragma unroll
    for (int r = 0; r < RPW; ++r) {
      a_out[b * N_ + i0 + wave * RPW + r] = acc[r];
      s1 += acc[r];
      s2 = fmaf(acc[r], acc[r], s2);
    }
    red4[wave] = make_float2(s1, s2);
  }
  __syncthreads();
  if (tid == 0) {
    float2 t = red4[0];
    t.x += red4[1].x + red4[2].x + red4[3].x;
    t.y += red4[1].y + red4[2].y + red4[3].y;
    part_out[b * CHUNKS + chunk] = t;
  }
}

// out[b,:] = res_in + gamma*(a-mean)/(sqrt(var_unbiased)+eps) + beta
// One block per batch row; stats reduced redundantly per wave.
__global__ __launch_bounds__(256) void final_ln_kernel(
    const float* __restrict__ res_in, const float* __restrict__ a_prev,
    const float2* __restrict__ part_prev, const float* __restrict__ gamma,
    const float* __restrict__ beta, float* __restrict__ out)
{
  const int b = blockIdx.x;
  const int tid = threadIdx.x;
  const int lane = tid & 63;

  float2 p0 = part_prev[b * CHUNKS + lane];
  float2 p1 = part_prev[b * CHUNKS + 64 + lane];
  float s1 = p0.x + p1.x;
  float s2 = p0.y + p1.y;
#pragma unroll
  for (int off = 32; off; off >>= 1) {
    s1 += __shfl_xor(s1, off);
    s2 += __shfl_xor(s2, off);
  }
  const float mean = s1 * (1.f / N_);
  const float var = (s2 - s1 * mean) * (1.f / (N_ - 1));
  const float inv = 1.f / (sqrtf(var) + EPS_);

  for (int j = tid; j < N_; j += 256) {
    out[b * N_ + j] =
        res_in[b * N_ + j] + gamma[j] * (a_prev[b * N_ + j] - mean) * inv + beta[j];
  }
}

extern "C" void kernel_launch(void* const* d_in, const int* in_sizes, int n_in,
                              void* d_out, int out_size, void* d_ws, size_t ws_size,
                              hipStream_t stream) {
  const float* x     = (const float*)d_in[0];
  const float* WQ    = (const float*)d_in[1];  // [L,H,N]
  const float* WK    = (const float*)d_in[2];
  const float* WV    = (const float*)d_in[3];
  const float* W0    = (const float*)d_in[4];  // [L,H]
  const float* gamma = (const float*)d_in[5];
  const float* beta  = (const float*)d_in[6];
  float* out = (float*)d_out;

  // Workspace layout (floats); ws is ~256 MB, we use ~56 KB.
  float* ws = (float*)d_ws;
  float* a0 = ws;                 // [B,N]
  float* a1 = ws + 8192;          // [B,N]
  float* a2 = ws + 16384;         // [B,N]
  float* res1 = ws + 24576;       // [B,N]
  float* res2 = ws + 32768;       // [B,N]
  float2* p0 = (float2*)(ws + 40960);  // [B,CHUNKS]
  float2* p1 = (float2*)(ws + 43008);  // [B,CHUNKS]
  float2* p2 = (float2*)(ws + 45056);  // [B,CHUNKS]

  const int G = B_ * CHUNKS;  // 512 blocks

  // Layer 0: cur = x
  attn_layer_kernel<<<G, 256, 0, stream>>>(
      x, nullptr, nullptr, gamma, beta,
      WQ, WK, WV, W0, a0, p0, nullptr);
  // Layer 1: cur = x + LN(a0)  (writes res1)
  attn_layer_kernel<<<G, 256, 0, stream>>>(
      x, a0, p0, gamma, beta,
      WQ + H_ * N_, WK + H_ * N_, WV + H_ * N_, W0 + H_, a1, p1, res1);
  // Layer 2: cur = res1 + LN(a1)  (writes res2)
  attn_layer_kernel<<<G, 256, 0, stream>>>(
      res1, a1, p1, gamma, beta,
      WQ + 2 * H_ * N_, WK + 2 * H_ * N_, WV + 2 * H_ * N_, W0 + 2 * H_, a2, p2, res2);
  // Final: out = res2 + LN(a2)
  final_ln_kernel<<<B_, 256, 0, stream>>>(res2, a2, p2, gamma, beta, out);
}